// Round 7
// baseline (987.201 us; speedup 1.0000x reference)
//
#include <hip/hip_runtime.h>

// MoE FFN: D=1024, H=4096, E=8, top-2, T=4096 tokens, fp32 in/out, bf16 MFMA compute.
// R9: counted-vmcnt round (T4). R8 counters: ~12k cycles per K-tile vs ~600 of
// compute -> the per-tile s_waitcnt vmcnt(0) drain IS the kernel (1 block/CU,
// zero cross-block overlap; all CUs burst 64KB then drain). Fix per m201/m218:
// 4-slot LDS ring of 32-K subtiles; subtile g issued at iter g-3 (3 periods of
// lead); main-loop wait = vmcnt(12) (3 subtiles of 4 loads stay IN FLIGHT),
// drain-to-0 only in the last tail iterations. 2 barriers per subtile.
// Everything else (merged grouped dispatch, 256-pad, natural n-fastest order,
// verified chunk swizzle, setprio, epilogues) unchanged from R8.

#define T_TOKENS 4096
#define DM 1024
#define HID 4096
#define NE 8
#define MT_SH2 (T_TOKENS / 256)                  // 16 shared m-tiles (256-rows)
#define SLOTS_MAX (2 * T_TOKENS + 256 * NE)      // 10240 padded expert slots max
#define MT_EX2 (SLOTS_MAX / 256)                 // 40 expert m-tiles max

typedef __attribute__((ext_vector_type(8))) short short8;
typedef __attribute__((ext_vector_type(4))) float f32x4;
typedef unsigned short u16;

__device__ __forceinline__ u16 f2b(float f) {
    unsigned u = __builtin_bit_cast(unsigned, f);
    u += 0x7FFFu + ((u >> 16) & 1u);   // round-to-nearest-even
    return (u16)(u >> 16);
}

__device__ __forceinline__ uint4 load8(const u16* p) {
    return *(const uint4*)p;           // 8 bf16 = 16 B
}
__device__ __forceinline__ uint4 load8(const float* p) {
    const float4* q = (const float4*)p;
    float4 a = q[0], b = q[1];
    uint4 r;
    r.x = (unsigned)f2b(a.x) | ((unsigned)f2b(a.y) << 16);
    r.y = (unsigned)f2b(a.z) | ((unsigned)f2b(a.w) << 16);
    r.z = (unsigned)f2b(b.x) | ((unsigned)f2b(b.y) << 16);
    r.w = (unsigned)f2b(b.z) | ((unsigned)f2b(b.w) << 16);
    return r;
}

// async 16B global -> LDS (wave-uniform lds base + lane*16)
__device__ __forceinline__ void gld16(const u16* g, u16* lds) {
    __builtin_amdgcn_global_load_lds(
        (const __attribute__((address_space(1))) void*)g,
        (__attribute__((address_space(3))) void*)lds, 16, 0, 0);
}

// ---- fused fp32 -> bf16 conversion of all tensors --------------------------
constexpr long CN0 = (long)T_TOKENS * DM;        // x
constexpr long CN1 = CN0 + (long)HID * DM;       // sw1
constexpr long CN2 = CN1 + (long)DM * HID;       // sw2
constexpr long CN3 = CN2 + (long)NE * HID * DM;  // ew1
constexpr long CN4 = CN3 + (long)NE * DM * HID;  // ew2

template<bool FULL>
__global__ __launch_bounds__(256) void cvt_all_kernel(
    const float* __restrict__ x,  const float* __restrict__ sw1,
    const float* __restrict__ sw2, const float* __restrict__ ew1,
    const float* __restrict__ ew2,
    u16* __restrict__ xb, u16* __restrict__ sw1b, u16* __restrict__ sw2b,
    u16* __restrict__ ew1b, u16* __restrict__ ew2b) {
    long i = ((long)blockIdx.x * 256 + threadIdx.x) * 8;
    const float* s; u16* d; long base;
    if (i < CN0)      { s = x;   d = xb;   base = 0;   }
    else if (i < CN1) { s = sw1; d = sw1b; base = CN0; }
    else if (i < CN2) { s = sw2; d = sw2b; base = CN1; }
    else if (FULL && i < CN3) { s = ew1; d = ew1b; base = CN2; }
    else if (FULL && i < CN4) { s = ew2; d = ew2b; base = CN3; }
    else return;
    long j = i - base;
    *(uint4*)(d + j) = load8(s + j);
}

// ---- gating (fp32: bf16 logits would flip near-tie expert picks) -----------
__global__ __launch_bounds__(256) void gate_kernel(const float* __restrict__ x,
                                                   const float* __restrict__ gw,
                                                   int* __restrict__ cnt,
                                                   int2* __restrict__ topidx,
                                                   float2* __restrict__ topg) {
    int t = blockIdx.x * 4 + (threadIdx.x >> 6);
    int lane = threadIdx.x & 63;
    const float* xr = x + (long)t * DM;
    float s[NE];
#pragma unroll
    for (int e = 0; e < NE; e++) s[e] = 0.f;
    for (int i = lane; i < DM; i += 64) {
        float xv = xr[i];
#pragma unroll
        for (int e = 0; e < NE; e++) s[e] += xv * gw[e * DM + i];
    }
#pragma unroll
    for (int e = 0; e < NE; e++)
        for (int o = 32; o > 0; o >>= 1) s[e] += __shfl_down(s[e], o);
    if (lane == 0) {
        int i0 = 0; float l0 = s[0];
#pragma unroll
        for (int e = 1; e < NE; e++) if (s[e] > l0) { l0 = s[e]; i0 = e; }
        int i1 = -1; float l1 = -1e30f;
#pragma unroll
        for (int e = 0; e < NE; e++) if (e != i0 && s[e] > l1) { l1 = s[e]; i1 = e; }
        float e1 = __expf(l1 - l0);
        float inv = 1.f / (1.f + e1);
        topidx[t] = make_int2(i0, i1);
        topg[t]   = make_float2(inv, e1 * inv);
        atomicAdd(&cnt[i0], 1);
        atomicAdd(&cnt[i1], 1);
    }
}

// offs padded to 256-aligned ranges: every expert m-tile is FULL (padding
// slots have tok=0/gate=0 from the memset -> contribute exactly 0 in L2).
__global__ void prefix_kernel(const int* __restrict__ cnt, int* __restrict__ offs) {
    if (threadIdx.x == 0) {
        int a = 0;
        for (int e = 0; e < NE; e++) {
            offs[e] = a;
            a += cnt[e];
            a = (a + 255) & ~255;
        }
        offs[NE] = a;   // total padded slots
    }
}

__global__ __launch_bounds__(256) void scatter_kernel(const int2* __restrict__ topidx,
                                                      const float2* __restrict__ topg,
                                                      const int* __restrict__ offs,
                                                      int* __restrict__ fill,
                                                      int* __restrict__ tok,
                                                      float* __restrict__ gate) {
    int t = blockIdx.x * 256 + threadIdx.x;
    if (t >= T_TOKENS) return;
    int2 ix = topidx[t]; float2 g = topg[t];
    int p = atomicAdd(&fill[ix.x], 1);
    int sl = offs[ix.x] + p;
    tok[sl] = t; gate[sl] = g.x;
    p = atomicAdd(&fill[ix.y], 1);
    sl = offs[ix.y] + p;
    tok[sl] = t; gate[sl] = g.y;
}

// ---- merged grouped GEMM, 256x256 tile, 8 waves, counted-vmcnt pipeline ----
// C[M,N] = A[M,K] * B[N,K]^T, bf16. 1D grid, natural order, n fastest.
// LDS: 4-slot ring; slot = one 32-K subtile of A and B (256x32 each, 16KB+16KB)
// -> 128 KB total. Within a subtile the verified chunk swizzle: physical
// chunk = row*4 + (kg ^ ((row>>1)&3)); global_load_lds dest linear, swizzle
// applied on the per-lane GLOBAL source address.
// Pipeline over subtiles g = 0..NG-1 (NG = K/32):
//   prologue: issue g=0,1,2 (12 loads/wave in flight)
//   iter g: issue g+3 into slot (g+3)&3 -> s_waitcnt vmcnt(12) [subtile g
//   landed; g+1..g+3 STAY IN FLIGHT] -> barrier -> 32 MFMA from slot g&3
//   (setprio) -> barrier. Tail counts 8/4/0 only in the last 3 iterations.
// Race audit: slot (g+3)&3 was last read at compute(g-1), sealed by that
// iteration's post-compute barrier (rendezvous precedes any wave's issue);
// each thread's DMA dest address is iteration-invariant, so the only WAW is
// my own wave's prior DMA, ordered by my own counted vmcnt (FIFO).
// PHASE 1: K=DM,  N=HID; silu -> bf16 into hS (shared) / hE (slots)
// PHASE 2: K=HID, N=DM;  atomicAdd f32 into pre-zeroed out
template<int PHASE>
__global__ __launch_bounds__(512, 2)
void gemm_moe256(const u16* __restrict__ Ash, const u16* __restrict__ Aex,
                 const u16* __restrict__ Bsh, const u16* __restrict__ Bex,
                 const int* __restrict__ offs,
                 const int* __restrict__ tok, const float* __restrict__ gate,
                 u16* __restrict__ hS, u16* __restrict__ hE,
                 float* __restrict__ out) {
    constexpr int KK = (PHASE == 1) ? DM : HID;
    constexpr int NX = (PHASE == 1) ? HID / 256 : DM / 256;
    constexpr long strideB = (long)HID * DM;

    const int wg = blockIdx.x;            // natural order (no swizzle)
    const int n0 = (wg % NX) * 256;
    const int mt = wg / NX;

    const bool sh = (mt < MT_SH2);
    int m0;
    const u16* Ab;
    const u16* B;
    if (sh) {
        m0 = mt * 256;
        Ab = Ash; B = Bsh;
    } else {
        m0 = (mt - MT_SH2) * 256;
        if (m0 >= offs[NE]) return;      // beyond padded total (block-uniform)
        int e = 0;
#pragma unroll
        for (int k = 1; k < NE; k++) e += (m0 >= offs[k]);
        Ab = Aex;
        B = Bex + (long)e * strideB;
    }

    __shared__ u16 As[4][256 * 32];   // [slot][row*32 + swizzled chunk], 16KB/slot
    __shared__ u16 Bs[4][256 * 32];

    const int tid  = threadIdx.x;
    const int lane = tid & 63;
    const int wid  = tid >> 6;           // 0..7
    const int wm   = (wid >> 2) * 128;   // wave M offset: 0 / 128
    const int wn   = (wid & 3) * 64;     // wave N offset: 0 / 64 / 128 / 192
    const int lr   = lane & 15;

    // Staging coords: within a subtile, round h covers physical chunks
    // p = h*512 + tid. row = h*128 + (tid>>2); swizzled k-chunk invariant.
    const int srow = tid >> 2;                        // 0..127
    const int skg  = (tid & 3) ^ ((srow >> 1) & 3);   // same for both halves
    long ar0, ar1;
    if (sh)                        { ar0 = m0 + srow;       ar1 = m0 + srow + 128; }
    else if constexpr (PHASE == 1) { ar0 = tok[m0 + srow];  ar1 = tok[m0 + srow + 128]; }
    else                           { ar0 = m0 + srow;       ar1 = m0 + srow + 128; }
    const u16* aP[2] = { Ab + ar0 * (long)KK + skg * 8,
                         Ab + ar1 * (long)KK + skg * 8 };
    const u16* bP[2] = { B + (long)(n0 + srow) * (long)KK + skg * 8,
                         B + (long)(n0 + srow + 128) * (long)KK + skg * 8 };
    const int ldsoff[2] = { (wid * 64) * 8, (512 + wid * 64) * 8 };

    // Fragment read offsets (elements within a subtile).
    const int key = (lr >> 1) & 3;
    const int kgx = (lane >> 4) ^ key;
    const int aoe = (wm + lr) * 32 + kgx * 8;
    const int boe = (wn + lr) * 32 + kgx * 8;

    f32x4 acc[8][4];
#pragma unroll
    for (int mi = 0; mi < 8; mi++)
#pragma unroll
        for (int ni = 0; ni < 4; ni++)
            acc[mi][ni] = (f32x4){0.f, 0.f, 0.f, 0.f};

    auto stage_sub = [&](int slot, int g) {   // 4 gld16/thread (A,B x 2 halves)
        const long kb = (long)g * 32;
#pragma unroll
        for (int h = 0; h < 2; h++) {
            gld16(aP[h] + kb, &As[slot][ldsoff[h]]);
            gld16(bP[h] + kb, &Bs[slot][ldsoff[h]]);
        }
    };
    auto compute_sub = [&](int slot) {
        const u16* Ac = &As[slot][0];
        const u16* Bc = &Bs[slot][0];
        short8 af[8], bf[4];
#pragma unroll
        for (int mi = 0; mi < 8; mi++) af[mi] = *(const short8*)&Ac[aoe + mi * 512];
#pragma unroll
        for (int ni = 0; ni < 4; ni++) bf[ni] = *(const short8*)&Bc[boe + ni * 512];
        __builtin_amdgcn_s_setprio(1);
#pragma unroll
        for (int mi = 0; mi < 8; mi++)
#pragma unroll
            for (int ni = 0; ni < 4; ni++)
                acc[mi][ni] = __builtin_amdgcn_mfma_f32_16x16x32_bf16(
                    af[mi], bf[ni], acc[mi][ni], 0, 0, 0);
        __builtin_amdgcn_s_setprio(0);
    };

    const int NG = KK >> 5;              // 32-K subtiles: 32 (P1) / 128 (P2)

    stage_sub(0, 0);
    stage_sub(1, 1);
    stage_sub(2, 2);

    for (int g = 0; g < NG; ++g) {
        if (g + 3 < NG) stage_sub((g + 3) & 3, g + 3);
        const int rem = NG - 1 - g;      // subtiles allowed to stay in flight
        if (rem >= 3)      asm volatile("s_waitcnt vmcnt(12)" ::: "memory");
        else if (rem == 2) asm volatile("s_waitcnt vmcnt(8)"  ::: "memory");
        else if (rem == 1) asm volatile("s_waitcnt vmcnt(4)"  ::: "memory");
        else               asm volatile("s_waitcnt vmcnt(0)"  ::: "memory");
        __builtin_amdgcn_s_barrier();    // all waves' subtile-g DMA landed
        asm volatile("" ::: "memory");
        compute_sub(g & 3);
        __builtin_amdgcn_s_barrier();    // slot g&3 sealed for overwrite
        asm volatile("" ::: "memory");
    }

    // Epilogue. C/D layout: col = lane&15, row = (lane>>4)*4 + reg  [m89-verified]
    const int r4 = (lane >> 4) * 4;
    const int cl = lane & 15;
#pragma unroll
    for (int mi = 0; mi < 8; mi++) {
#pragma unroll
        for (int rr = 0; rr < 4; rr++) {
            int row = m0 + wm + mi * 16 + r4 + rr;
            int tt = 0; float g = 0.f;
            if constexpr (PHASE == 2) {
                if (!sh) { tt = tok[row]; g = gate[row]; }
            }
#pragma unroll
            for (int ni = 0; ni < 4; ni++) {
                int col = n0 + wn + ni * 16 + cl;
                float v = acc[mi][ni][rr];
                if constexpr (PHASE == 1) {
                    float s2 = v / (1.f + __expf(-v));
                    if (sh) hS[(long)row * HID + col] = f2b(s2);
                    else    hE[(long)row * HID + col] = f2b(s2);
                } else {
                    if (sh) atomicAdd(&out[(long)row * DM + col], v);
                    else    atomicAdd(&out[(long)tt * DM + col], g * v);
                }
            }
        }
    }
}

// ---- fallback sync GEMM (fp32 B in-flight convert) for small-ws case -------
template<typename TB, int MODE>
__global__ __launch_bounds__(256)
void gemm_bt(const u16* __restrict__ A, int lda,
             const TB* __restrict__ Bbase, int ldb, long strideB, int K,
             int Mstatic,
             const int* __restrict__ cnt, const int* __restrict__ offs,
             const int* __restrict__ tok_of_slot, const float* __restrict__ gate_of_slot,
             u16* __restrict__ Cb, int ldcb,
             float* __restrict__ Cf, int ldcf) {
    int M = Mstatic, base = 0;
    const TB* B = Bbase;
    if constexpr (MODE >= 2) {
        int e = blockIdx.z;
        base = offs[e];
        M = cnt[e];
        B = Bbase + (long)e * strideB;
    }
    const int m0 = blockIdx.y * 128;
    if (m0 >= M) return;
    const int n0 = blockIdx.x * 128;

    __shared__ u16 As[128][40];
    __shared__ u16 Bs[128][40];

    const int tid  = threadIdx.x;
    const int lane = tid & 63;
    const int wid  = tid >> 6;
    const int wm   = (wid >> 1) * 64;
    const int wn   = (wid & 1) * 64;
    const int lr   = lane & 15;
    const int lk   = (lane >> 4) * 8;

    int arow_r[2], akc[2];
    long aoff[2], boff[2];
#pragma unroll
    for (int i = 0; i < 2; i++) {
        int c = tid + i * 256;
        int r = c >> 2, kc = (c & 3) * 8;
        arow_r[i] = r; akc[i] = kc;
        int rr = m0 + r;
        if (rr >= M) rr = M - 1;
        long grow;
        if constexpr (MODE == 2)      grow = tok_of_slot[base + rr];
        else if constexpr (MODE == 3) grow = (long)(base + rr);
        else                          grow = rr;
        aoff[i] = grow * (long)lda + kc;
        boff[i] = (long)(n0 + r) * ldb + kc;
    }

    f32x4 acc[4][4];
#pragma unroll
    for (int mi = 0; mi < 4; mi++)
#pragma unroll
        for (int ni = 0; ni < 4; ni++)
            acc[mi][ni] = (f32x4){0.f, 0.f, 0.f, 0.f};

    for (int k0 = 0; k0 < K; k0 += 32) {
#pragma unroll
        for (int i = 0; i < 2; i++) {
            *(uint4*)&As[arow_r[i]][akc[i]] = load8(A + aoff[i] + k0);
            *(uint4*)&Bs[arow_r[i]][akc[i]] = load8(B + boff[i] + k0);
        }
        __syncthreads();
        short8 af[4], bfr[4];
#pragma unroll
        for (int mi = 0; mi < 4; mi++) af[mi]  = *(const short8*)&As[wm + mi * 16 + lr][lk];
#pragma unroll
        for (int ni = 0; ni < 4; ni++) bfr[ni] = *(const short8*)&Bs[wn + ni * 16 + lr][lk];
#pragma unroll
        for (int mi = 0; mi < 4; mi++)
#pragma unroll
            for (int ni = 0; ni < 4; ni++)
                acc[mi][ni] = __builtin_amdgcn_mfma_f32_16x16x32_bf16(af[mi], bfr[ni],
                                                                      acc[mi][ni], 0, 0, 0);
        __syncthreads();
    }

    const int r4 = (lane >> 4) * 4;
    const int cl = lane & 15;
#pragma unroll
    for (int mi = 0; mi < 4; mi++) {
#pragma unroll
        for (int rr = 0; rr < 4; rr++) {
            int row = m0 + wm + mi * 16 + r4 + rr;
            if constexpr (MODE >= 2) { if (row >= M) continue; }
            int t = 0; float g = 0.f;
            if constexpr (MODE == 3) {
                t = tok_of_slot[base + row];
                g = gate_of_slot[base + row];
            }
#pragma unroll
            for (int ni = 0; ni < 4; ni++) {
                int col = n0 + wn + ni * 16 + cl;
                float v = acc[mi][ni][rr];
                if constexpr (MODE == 2) {
                    float s = v / (1.f + __expf(-v));
                    Cb[(long)(base + row) * ldcb + col] = f2b(s);
                } else if constexpr (MODE == 3) {
                    atomicAdd(&Cf[(long)t * ldcf + col], g * v);
                }
            }
        }
    }
}

extern "C" void kernel_launch(void* const* d_in, const int* in_sizes, int n_in,
                              void* d_out, int out_size, void* d_ws, size_t ws_size,
                              hipStream_t stream) {
    const float* x   = (const float*)d_in[0];
    const float* sw1 = (const float*)d_in[1];
    const float* sw2 = (const float*)d_in[2];
    const float* ew1 = (const float*)d_in[3];
    const float* ew2 = (const float*)d_in[4];
    const float* gw  = (const float*)d_in[5];
    float* out = (float*)d_out;

    char* ws = (char*)d_ws;
    size_t off = 0;
    auto alloc = [&](size_t bytes) -> char* {
        off = (off + 255) & ~(size_t)255;
        char* p = ws + off;
        off += bytes;
        return p;
    };

    int*    meta   = (int*)alloc(256);          // cnt[8] | fill[8] | offs[9]
    int*    cnt    = meta;
    int*    fill   = meta + 8;
    int*    offs   = meta + 16;
    int2*   topidx = (int2*)alloc((size_t)T_TOKENS * 8);
    float2* topg   = (float2*)alloc((size_t)T_TOKENS * 8);
    int*    tok    = (int*)alloc((size_t)SLOTS_MAX * 4);
    float*  gate   = (float*)alloc((size_t)SLOTS_MAX * 4);
    u16* xb   = (u16*)alloc((size_t)T_TOKENS * DM * 2);
    u16* sw1b = (u16*)alloc((size_t)HID * DM * 2);
    u16* sw2b = (u16*)alloc((size_t)DM * HID * 2);
    u16* hidS = (u16*)alloc((size_t)T_TOKENS * HID * 2);
    u16* hidE = (u16*)alloc((size_t)SLOTS_MAX * HID * 2);

    const size_t ew_bytes = (size_t)NE * HID * DM * 2;   // 64 MB each
    bool cvt_ew = (ws_size >= off + 2 * ew_bytes + 1024);
    u16 *ew1b = nullptr, *ew2b = nullptr;
    if (cvt_ew) {
        ew1b = (u16*)alloc(ew_bytes);
        ew2b = (u16*)alloc(ew_bytes);
    }

    hipMemsetAsync(meta, 0, 64, stream);                         // cnt+fill
    hipMemsetAsync(tok, 0, (size_t)SLOTS_MAX * 4, stream);       // padding -> token 0
    hipMemsetAsync(gate, 0, (size_t)SLOTS_MAX * 4, stream);      // padding -> gate 0
    hipMemsetAsync(out, 0, (size_t)T_TOKENS * DM * 4, stream);   // L2 is all-atomicAdd

    if (cvt_ew)
        cvt_all_kernel<true><<<(int)(CN4 / 2048), 256, 0, stream>>>(
            x, sw1, sw2, ew1, ew2, xb, sw1b, sw2b, ew1b, ew2b);
    else
        cvt_all_kernel<false><<<(int)(CN2 / 2048), 256, 0, stream>>>(
            x, sw1, sw2, nullptr, nullptr, xb, sw1b, sw2b, nullptr, nullptr);

    gate_kernel<<<T_TOKENS / 4, 256, 0, stream>>>(x, gw, cnt, topidx, topg);
    prefix_kernel<<<1, 64, 0, stream>>>(cnt, offs);
    scatter_kernel<<<T_TOKENS / 256, 256, 0, stream>>>(topidx, topg, offs, fill, tok, gate);

    dim3 blk(512);
    if (cvt_ew) {
        // L1 merged: shared (16 m-tiles) + experts (<=40 padded m-tiles), N=HID
        gemm_moe256<1><<<dim3((MT_SH2 + MT_EX2) * (HID / 256)), blk, 0, stream>>>(
            xb, xb, sw1b, ew1b, offs, tok, gate, hidS, hidE, nullptr);
        // L2 merged: N=DM, all-atomicAdd into pre-zeroed out
        gemm_moe256<2><<<dim3((MT_SH2 + MT_EX2) * (DM / 256)), blk, 0, stream>>>(
            hidS, hidE, sw2b, ew2b, offs, tok, gate, nullptr, nullptr, out);
    } else {
        // shared-only via gemm_moe256 (grid limited to shared section),
        // experts via in-flight-convert fallback (real slot counts only).
        gemm_moe256<1><<<dim3(MT_SH2 * (HID / 256)), blk, 0, stream>>>(
            xb, xb, sw1b, nullptr, offs, tok, gate, hidS, nullptr, nullptr);
        gemm_bt<float, 2><<<dim3(HID / 128, T_TOKENS / 128, NE), dim3(256), 0, stream>>>(
            xb, DM, ew1, DM, (long)HID * DM, DM, 0,
            cnt, offs, tok, gate, hidE, HID, nullptr, 0);
        gemm_moe256<2><<<dim3(MT_SH2 * (DM / 256)), blk, 0, stream>>>(
            hidS, hidE, sw2b, nullptr, offs, tok, gate, nullptr, nullptr, out);
        gemm_bt<float, 3><<<dim3(DM / 128, T_TOKENS / 128, NE), dim3(256), 0, stream>>>(
            hidE, HID, ew2, HID, (long)DM * HID, HID, 0,
            cnt, offs, tok, gate, nullptr, 0, out, DM);
    }
}

// Round 8
// 941.057 us; speedup vs baseline: 1.0490x; 1.0490x over previous
//
#include <hip/hip_runtime.h>

// MoE FFN: D=1024, H=4096, E=8, top-2, T=4096 tokens, fp32 in/out, bf16 MFMA compute.
// R10: genuine m201 8-phase port. R8/R9 were "coarse phase-split without the
// fine ds_read||G-load||MFMA interleave" -- exactly the pattern m196 measured
// as a LOSS vs the real 8-phase (m196->m198 +28-41% was the per-phase
// interleave itself). Structure here, per 64-K tile: 4 phases of
// {issue 1 x 16KB stage-unit -> (ks-start: vmcnt(10)+barrier) -> 4-8
// ds_read_b128 -> setprio(1) 16 MFMA setprio(0) -> barrier}. 2 dbuf x 4 units
// (unit = one matrix x 32-K half, verified zero-conflict chunk swizzle);
// 5 units / 10 loads stay in flight at steady state; drains only at the tail.
// Merged shared+expert grouped dispatch, 256-pad, natural n-fastest order.

#define T_TOKENS 4096
#define DM 1024
#define HID 4096
#define NE 8
#define MT_SH2 (T_TOKENS / 256)                  // 16 shared m-tiles (256-rows)
#define SLOTS_MAX (2 * T_TOKENS + 256 * NE)      // 10240 padded expert slots max
#define MT_EX2 (SLOTS_MAX / 256)                 // 40 expert m-tiles max

typedef __attribute__((ext_vector_type(8))) short short8;
typedef __attribute__((ext_vector_type(4))) float f32x4;
typedef unsigned short u16;

__device__ __forceinline__ u16 f2b(float f) {
    unsigned u = __builtin_bit_cast(unsigned, f);
    u += 0x7FFFu + ((u >> 16) & 1u);   // round-to-nearest-even
    return (u16)(u >> 16);
}

__device__ __forceinline__ uint4 load8(const u16* p) {
    return *(const uint4*)p;           // 8 bf16 = 16 B
}
__device__ __forceinline__ uint4 load8(const float* p) {
    const float4* q = (const float4*)p;
    float4 a = q[0], b = q[1];
    uint4 r;
    r.x = (unsigned)f2b(a.x) | ((unsigned)f2b(a.y) << 16);
    r.y = (unsigned)f2b(a.z) | ((unsigned)f2b(a.w) << 16);
    r.z = (unsigned)f2b(b.x) | ((unsigned)f2b(b.y) << 16);
    r.w = (unsigned)f2b(b.z) | ((unsigned)f2b(b.w) << 16);
    return r;
}

// async 16B global -> LDS (wave-uniform lds base + lane*16)
__device__ __forceinline__ void gld16(const u16* g, u16* lds) {
    __builtin_amdgcn_global_load_lds(
        (const __attribute__((address_space(1))) void*)g,
        (__attribute__((address_space(3))) void*)lds, 16, 0, 0);
}

#define BARRIER() do { __builtin_amdgcn_s_barrier(); asm volatile("" ::: "memory"); } while (0)

// ---- fused fp32 -> bf16 conversion of all tensors --------------------------
constexpr long CN0 = (long)T_TOKENS * DM;        // x
constexpr long CN1 = CN0 + (long)HID * DM;       // sw1
constexpr long CN2 = CN1 + (long)DM * HID;       // sw2
constexpr long CN3 = CN2 + (long)NE * HID * DM;  // ew1
constexpr long CN4 = CN3 + (long)NE * DM * HID;  // ew2

template<bool FULL>
__global__ __launch_bounds__(256) void cvt_all_kernel(
    const float* __restrict__ x,  const float* __restrict__ sw1,
    const float* __restrict__ sw2, const float* __restrict__ ew1,
    const float* __restrict__ ew2,
    u16* __restrict__ xb, u16* __restrict__ sw1b, u16* __restrict__ sw2b,
    u16* __restrict__ ew1b, u16* __restrict__ ew2b) {
    long i = ((long)blockIdx.x * 256 + threadIdx.x) * 8;
    const float* s; u16* d; long base;
    if (i < CN0)      { s = x;   d = xb;   base = 0;   }
    else if (i < CN1) { s = sw1; d = sw1b; base = CN0; }
    else if (i < CN2) { s = sw2; d = sw2b; base = CN1; }
    else if (FULL && i < CN3) { s = ew1; d = ew1b; base = CN2; }
    else if (FULL && i < CN4) { s = ew2; d = ew2b; base = CN3; }
    else return;
    long j = i - base;
    *(uint4*)(d + j) = load8(s + j);
}

// ---- gating (fp32: bf16 logits would flip near-tie expert picks) -----------
__global__ __launch_bounds__(256) void gate_kernel(const float* __restrict__ x,
                                                   const float* __restrict__ gw,
                                                   int* __restrict__ cnt,
                                                   int2* __restrict__ topidx,
                                                   float2* __restrict__ topg) {
    int t = blockIdx.x * 4 + (threadIdx.x >> 6);
    int lane = threadIdx.x & 63;
    const float* xr = x + (long)t * DM;
    float s[NE];
#pragma unroll
    for (int e = 0; e < NE; e++) s[e] = 0.f;
    for (int i = lane; i < DM; i += 64) {
        float xv = xr[i];
#pragma unroll
        for (int e = 0; e < NE; e++) s[e] += xv * gw[e * DM + i];
    }
#pragma unroll
    for (int e = 0; e < NE; e++)
        for (int o = 32; o > 0; o >>= 1) s[e] += __shfl_down(s[e], o);
    if (lane == 0) {
        int i0 = 0; float l0 = s[0];
#pragma unroll
        for (int e = 1; e < NE; e++) if (s[e] > l0) { l0 = s[e]; i0 = e; }
        int i1 = -1; float l1 = -1e30f;
#pragma unroll
        for (int e = 0; e < NE; e++) if (e != i0 && s[e] > l1) { l1 = s[e]; i1 = e; }
        float e1 = __expf(l1 - l0);
        float inv = 1.f / (1.f + e1);
        topidx[t] = make_int2(i0, i1);
        topg[t]   = make_float2(inv, e1 * inv);
        atomicAdd(&cnt[i0], 1);
        atomicAdd(&cnt[i1], 1);
    }
}

// offs padded to 256-aligned ranges: every expert m-tile is FULL (padding
// slots have tok=0/gate=0 from the memset -> contribute exactly 0 in L2).
__global__ void prefix_kernel(const int* __restrict__ cnt, int* __restrict__ offs) {
    if (threadIdx.x == 0) {
        int a = 0;
        for (int e = 0; e < NE; e++) {
            offs[e] = a;
            a += cnt[e];
            a = (a + 255) & ~255;
        }
        offs[NE] = a;   // total padded slots
    }
}

__global__ __launch_bounds__(256) void scatter_kernel(const int2* __restrict__ topidx,
                                                      const float2* __restrict__ topg,
                                                      const int* __restrict__ offs,
                                                      int* __restrict__ fill,
                                                      int* __restrict__ tok,
                                                      float* __restrict__ gate) {
    int t = blockIdx.x * 256 + threadIdx.x;
    if (t >= T_TOKENS) return;
    int2 ix = topidx[t]; float2 g = topg[t];
    int p = atomicAdd(&fill[ix.x], 1);
    int sl = offs[ix.x] + p;
    tok[sl] = t; gate[sl] = g.x;
    p = atomicAdd(&fill[ix.y], 1);
    sl = offs[ix.y] + p;
    tok[sl] = t; gate[sl] = g.y;
}

// ---- merged grouped GEMM, 256x256, BK=64, 8 waves, m201 8-phase schedule ---
// C[M,N] = A[M,K] * B[N,K]^T, bf16. 1D grid, natural order, n fastest.
// LDS: As/Bs[2 dbuf][2 ks][256 rows x 32 K] -- 4 "units" of 16KB per K-tile
// (unit u: tile j=u>>2, ks=(u>>1)&1, matrix=u&1 in order Ak0,Bk0,Ak1,Bk1).
// Chunk swizzle (verified 0-conflict): chunk p = row*4 + (kg^((row>>1)&3));
// gld16 dest linear, swizzle on the per-lane global source address.
// Phase plan per K-tile j (phases p = (ks,mh)):
//   p: [issue unit isd++ if any] [p even: vmcnt + BARRIER] [ds_read 4-8 frags]
//      [p odd: BARRIER] setprio(1) 16 MFMA setprio(0) BARRIER
// Steady state: 5 units / 10 loads in flight -> vmcnt(10); tail 8/4/0.
// WAR audit (lead 6 units): writes at phase p of tile j target units of tile
// j+1 (p=0,1; other dbuf, last read tile j-1, sealed) or tile j+2 units
// ks0 (p=2,3; same dbuf, last read phases 0/1 of tile j, sealed by phase-1's
// final barrier which precedes phase-2's issue). All reads of unit (j,ks)
// occur in phases 2ks/2ks+1, after the vmcnt+barrier that covers it.
// PHASE 1: K=DM,  N=HID; silu -> bf16 into hS (shared) / hE (slots)
// PHASE 2: K=HID, N=DM;  atomicAdd f32 into pre-zeroed out
template<int PHASE>
__global__ __launch_bounds__(512, 2)
void gemm_moe256(const u16* __restrict__ Ash, const u16* __restrict__ Aex,
                 const u16* __restrict__ Bsh, const u16* __restrict__ Bex,
                 const int* __restrict__ offs,
                 const int* __restrict__ tok, const float* __restrict__ gate,
                 u16* __restrict__ hS, u16* __restrict__ hE,
                 float* __restrict__ out) {
    constexpr int KK = (PHASE == 1) ? DM : HID;
    constexpr int NX = (PHASE == 1) ? HID / 256 : DM / 256;
    constexpr long strideB = (long)HID * DM;

    const int wg = blockIdx.x;            // natural order (no swizzle)
    const int n0 = (wg % NX) * 256;
    const int mt = wg / NX;

    const bool sh = (mt < MT_SH2);
    int m0;
    const u16* Ab;
    const u16* B;
    if (sh) {
        m0 = mt * 256;
        Ab = Ash; B = Bsh;
    } else {
        m0 = (mt - MT_SH2) * 256;
        if (m0 >= offs[NE]) return;      // beyond padded total (block-uniform)
        int e = 0;
#pragma unroll
        for (int k = 1; k < NE; k++) e += (m0 >= offs[k]);
        Ab = Aex;
        B = Bex + (long)e * strideB;
    }

    __shared__ u16 As[2][2][256 * 32];   // [dbuf][ks][row*32 + swz chunk] 16KB/unit
    __shared__ u16 Bs[2][2][256 * 32];

    const int tid  = threadIdx.x;
    const int lane = tid & 63;
    const int wid  = tid >> 6;           // 0..7
    const int wm   = (wid >> 2) * 128;   // wave M offset: 0 / 128
    const int wn   = (wid & 3) * 64;     // wave N offset: 0/64/128/192
    const int lr   = lane & 15;

    // Staging: one unit = 1024 chunks of 16B; thread covers p = i*512+tid.
    const u16* aP[2]; const u16* bP[2]; int ldso[2];
#pragma unroll
    for (int i = 0; i < 2; i++) {
        int p = i * 512 + tid;
        int r = p >> 2;                                // 0..255
        int kg = (p & 3) ^ ((r >> 1) & 3);
        long arow;
        if (sh)                        arow = m0 + r;
        else if constexpr (PHASE == 1) arow = tok[m0 + r];
        else                           arow = m0 + r;
        aP[i] = Ab + arow * (long)KK + kg * 8;
        bP[i] = B + (long)(n0 + r) * KK + kg * 8;
        ldso[i] = (i * 512 + wid * 64) * 8;            // wave-uniform base
    }

    // Fragment read offsets within a unit (verified conflict-free pattern).
    const int key = (lr >> 1) & 3;
    const int kgx = (lane >> 4) ^ key;
    const int aoe = (wm + lr) * 32 + kgx * 8;
    const int boe = (wn + lr) * 32 + kgx * 8;

    f32x4 acc[8][4];
#pragma unroll
    for (int mi = 0; mi < 8; mi++)
#pragma unroll
        for (int ni = 0; ni < 4; ni++)
            acc[mi][ni] = (f32x4){0.f, 0.f, 0.f, 0.f};

    auto stage_unit = [&](int u) {       // 2 gld16/thread (16KB block-wide)
        const int jj = u >> 2, ks = (u >> 1) & 1, isB = u & 1;
        const long kb = (long)jj * 64 + ks * 32;
        u16* dst = isB ? &Bs[jj & 1][ks][0] : &As[jj & 1][ks][0];
        const u16* const* gp = isB ? bP : aP;
#pragma unroll
        for (int i = 0; i < 2; i++) gld16(gp[i] + kb, dst + ldso[i]);
    };

    const int nt  = KK >> 6;             // 64-K tiles: 16 (P1) / 64 (P2)
    const int NTU = nt * 4;              // total stage units
    int isd = 0;
    for (; isd < 6; ++isd) stage_unit(isd);   // prologue: 6 units / 12 loads

#define ISSUE() do { if (isd < NTU) { stage_unit(isd); ++isd; } } while (0)
#define MFMA16(A_, B_, MH_) do {                                              \
    __builtin_amdgcn_s_setprio(1);                                            \
    _Pragma("unroll")                                                         \
    for (int m_ = 0; m_ < 4; m_++)                                            \
        _Pragma("unroll")                                                     \
        for (int n_ = 0; n_ < 4; n_++)                                        \
            acc[(MH_) * 4 + m_][n_] = __builtin_amdgcn_mfma_f32_16x16x32_bf16(\
                (A_)[m_], (B_)[n_], acc[(MH_) * 4 + m_][n_], 0, 0, 0);        \
    __builtin_amdgcn_s_setprio(0);                                            \
} while (0)

    for (int j = 0; j < nt; ++j) {
        const int cb  = j & 1;
        const int rem = nt - 1 - j;
        // ---- phase 0 (ks=0, mh=0) ----
        ISSUE();
        if (rem >= 1) asm volatile("s_waitcnt vmcnt(10)" ::: "memory");
        else          asm volatile("s_waitcnt vmcnt(4)"  ::: "memory");
        BARRIER();                       // units (j,Ak0),(j,Bk0) landed, all waves
        short8 b0[4], a0[4];
#pragma unroll
        for (int n_ = 0; n_ < 4; n_++) b0[n_] = *(const short8*)&Bs[cb][0][boe + n_ * 512];
#pragma unroll
        for (int m_ = 0; m_ < 4; m_++) a0[m_] = *(const short8*)&As[cb][0][aoe + m_ * 512];
        MFMA16(a0, b0, 0);
        BARRIER();
        // ---- phase 1 (ks=0, mh=1) ----
        ISSUE();
        short8 a1[4];
#pragma unroll
        for (int m_ = 0; m_ < 4; m_++) a1[m_] = *(const short8*)&As[cb][0][aoe + (4 + m_) * 512];
        BARRIER();
        MFMA16(a1, b0, 1);
        BARRIER();
        // ---- phase 2 (ks=1, mh=0) ----
        ISSUE();
        if (rem >= 2)      asm volatile("s_waitcnt vmcnt(10)" ::: "memory");
        else if (rem == 1) asm volatile("s_waitcnt vmcnt(8)"  ::: "memory");
        else               asm volatile("s_waitcnt vmcnt(0)"  ::: "memory");
        BARRIER();                       // units (j,Ak1),(j,Bk1) landed
        short8 b1[4], a2[4];
#pragma unroll
        for (int n_ = 0; n_ < 4; n_++) b1[n_] = *(const short8*)&Bs[cb][1][boe + n_ * 512];
#pragma unroll
        for (int m_ = 0; m_ < 4; m_++) a2[m_] = *(const short8*)&As[cb][1][aoe + m_ * 512];
        MFMA16(a2, b1, 0);
        BARRIER();
        // ---- phase 3 (ks=1, mh=1) ----
        ISSUE();
        short8 a3[4];
#pragma unroll
        for (int m_ = 0; m_ < 4; m_++) a3[m_] = *(const short8*)&As[cb][1][aoe + (4 + m_) * 512];
        BARRIER();
        MFMA16(a3, b1, 1);
        BARRIER();
    }
#undef ISSUE
#undef MFMA16

    // Epilogue. C/D layout: col = lane&15, row = (lane>>4)*4 + reg  [m89-verified]
    const int r4 = (lane >> 4) * 4;
    const int cl = lane & 15;
#pragma unroll
    for (int mi = 0; mi < 8; mi++) {
#pragma unroll
        for (int rr = 0; rr < 4; rr++) {
            int row = m0 + wm + mi * 16 + r4 + rr;
            int tt = 0; float g = 0.f;
            if constexpr (PHASE == 2) {
                if (!sh) { tt = tok[row]; g = gate[row]; }
            }
#pragma unroll
            for (int ni = 0; ni < 4; ni++) {
                int col = n0 + wn + ni * 16 + cl;
                float v = acc[mi][ni][rr];
                if constexpr (PHASE == 1) {
                    float s2 = v / (1.f + __expf(-v));
                    if (sh) hS[(long)row * HID + col] = f2b(s2);
                    else    hE[(long)row * HID + col] = f2b(s2);
                } else {
                    if (sh) atomicAdd(&out[(long)row * DM + col], v);
                    else    atomicAdd(&out[(long)tt * DM + col], g * v);
                }
            }
        }
    }
}

// ---- fallback sync GEMM (fp32 B in-flight convert) for small-ws case -------
template<typename TB, int MODE>
__global__ __launch_bounds__(256)
void gemm_bt(const u16* __restrict__ A, int lda,
             const TB* __restrict__ Bbase, int ldb, long strideB, int K,
             int Mstatic,
             const int* __restrict__ cnt, const int* __restrict__ offs,
             const int* __restrict__ tok_of_slot, const float* __restrict__ gate_of_slot,
             u16* __restrict__ Cb, int ldcb,
             float* __restrict__ Cf, int ldcf) {
    int M = Mstatic, base = 0;
    const TB* B = Bbase;
    if constexpr (MODE >= 2) {
        int e = blockIdx.z;
        base = offs[e];
        M = cnt[e];
        B = Bbase + (long)e * strideB;
    }
    const int m0 = blockIdx.y * 128;
    if (m0 >= M) return;
    const int n0 = blockIdx.x * 128;

    __shared__ u16 As[128][40];
    __shared__ u16 Bs[128][40];

    const int tid  = threadIdx.x;
    const int lane = tid & 63;
    const int wid  = tid >> 6;
    const int wm   = (wid >> 1) * 64;
    const int wn   = (wid & 1) * 64;
    const int lr   = lane & 15;
    const int lk   = (lane >> 4) * 8;

    int arow_r[2], akc[2];
    long aoff[2], boff[2];
#pragma unroll
    for (int i = 0; i < 2; i++) {
        int c = tid + i * 256;
        int r = c >> 2, kc = (c & 3) * 8;
        arow_r[i] = r; akc[i] = kc;
        int rr = m0 + r;
        if (rr >= M) rr = M - 1;
        long grow;
        if constexpr (MODE == 2)      grow = tok_of_slot[base + rr];
        else if constexpr (MODE == 3) grow = (long)(base + rr);
        else                          grow = rr;
        aoff[i] = grow * (long)lda + kc;
        boff[i] = (long)(n0 + r) * ldb + kc;
    }

    f32x4 acc[4][4];
#pragma unroll
    for (int mi = 0; mi < 4; mi++)
#pragma unroll
        for (int ni = 0; ni < 4; ni++)
            acc[mi][ni] = (f32x4){0.f, 0.f, 0.f, 0.f};

    for (int k0 = 0; k0 < K; k0 += 32) {
#pragma unroll
        for (int i = 0; i < 2; i++) {
            *(uint4*)&As[arow_r[i]][akc[i]] = load8(A + aoff[i] + k0);
            *(uint4*)&Bs[arow_r[i]][akc[i]] = load8(B + boff[i] + k0);
        }
        __syncthreads();
        short8 af[4], bfr[4];
#pragma unroll
        for (int mi = 0; mi < 4; mi++) af[mi]  = *(const short8*)&As[wm + mi * 16 + lr][lk];
#pragma unroll
        for (int ni = 0; ni < 4; ni++) bfr[ni] = *(const short8*)&Bs[wn + ni * 16 + lr][lk];
#pragma unroll
        for (int mi = 0; mi < 4; mi++)
#pragma unroll
            for (int ni = 0; ni < 4; ni++)
                acc[mi][ni] = __builtin_amdgcn_mfma_f32_16x16x32_bf16(af[mi], bfr[ni],
                                                                      acc[mi][ni], 0, 0, 0);
        __syncthreads();
    }

    const int r4 = (lane >> 4) * 4;
    const int cl = lane & 15;
#pragma unroll
    for (int mi = 0; mi < 4; mi++) {
#pragma unroll
        for (int rr = 0; rr < 4; rr++) {
            int row = m0 + wm + mi * 16 + r4 + rr;
            if constexpr (MODE >= 2) { if (row >= M) continue; }
            int t = 0; float g = 0.f;
            if constexpr (MODE == 3) {
                t = tok_of_slot[base + row];
                g = gate_of_slot[base + row];
            }
#pragma unroll
            for (int ni = 0; ni < 4; ni++) {
                int col = n0 + wn + ni * 16 + cl;
                float v = acc[mi][ni][rr];
                if constexpr (MODE == 2) {
                    float s = v / (1.f + __expf(-v));
                    Cb[(long)(base + row) * ldcb + col] = f2b(s);
                } else if constexpr (MODE == 3) {
                    atomicAdd(&Cf[(long)t * ldcf + col], g * v);
                }
            }
        }
    }
}

extern "C" void kernel_launch(void* const* d_in, const int* in_sizes, int n_in,
                              void* d_out, int out_size, void* d_ws, size_t ws_size,
                              hipStream_t stream) {
    const float* x   = (const float*)d_in[0];
    const float* sw1 = (const float*)d_in[1];
    const float* sw2 = (const float*)d_in[2];
    const float* ew1 = (const float*)d_in[3];
    const float* ew2 = (const float*)d_in[4];
    const float* gw  = (const float*)d_in[5];
    float* out = (float*)d_out;

    char* ws = (char*)d_ws;
    size_t off = 0;
    auto alloc = [&](size_t bytes) -> char* {
        off = (off + 255) & ~(size_t)255;
        char* p = ws + off;
        off += bytes;
        return p;
    };

    int*    meta   = (int*)alloc(256);          // cnt[8] | fill[8] | offs[9]
    int*    cnt    = meta;
    int*    fill   = meta + 8;
    int*    offs   = meta + 16;
    int2*   topidx = (int2*)alloc((size_t)T_TOKENS * 8);
    float2* topg   = (float2*)alloc((size_t)T_TOKENS * 8);
    int*    tok    = (int*)alloc((size_t)SLOTS_MAX * 4);
    float*  gate   = (float*)alloc((size_t)SLOTS_MAX * 4);
    u16* xb   = (u16*)alloc((size_t)T_TOKENS * DM * 2);
    u16* sw1b = (u16*)alloc((size_t)HID * DM * 2);
    u16* sw2b = (u16*)alloc((size_t)DM * HID * 2);
    u16* hidS = (u16*)alloc((size_t)T_TOKENS * HID * 2);
    u16* hidE = (u16*)alloc((size_t)SLOTS_MAX * HID * 2);

    const size_t ew_bytes = (size_t)NE * HID * DM * 2;   // 64 MB each
    bool cvt_ew = (ws_size >= off + 2 * ew_bytes + 1024);
    u16 *ew1b = nullptr, *ew2b = nullptr;
    if (cvt_ew) {
        ew1b = (u16*)alloc(ew_bytes);
        ew2b = (u16*)alloc(ew_bytes);
    }

    hipMemsetAsync(meta, 0, 64, stream);                         // cnt+fill
    hipMemsetAsync(tok, 0, (size_t)SLOTS_MAX * 4, stream);       // padding -> token 0
    hipMemsetAsync(gate, 0, (size_t)SLOTS_MAX * 4, stream);      // padding -> gate 0
    hipMemsetAsync(out, 0, (size_t)T_TOKENS * DM * 4, stream);   // L2 is all-atomicAdd

    if (cvt_ew)
        cvt_all_kernel<true><<<(int)(CN4 / 2048), 256, 0, stream>>>(
            x, sw1, sw2, ew1, ew2, xb, sw1b, sw2b, ew1b, ew2b);
    else
        cvt_all_kernel<false><<<(int)(CN2 / 2048), 256, 0, stream>>>(
            x, sw1, sw2, nullptr, nullptr, xb, sw1b, sw2b, nullptr, nullptr);

    gate_kernel<<<T_TOKENS / 4, 256, 0, stream>>>(x, gw, cnt, topidx, topg);
    prefix_kernel<<<1, 64, 0, stream>>>(cnt, offs);
    scatter_kernel<<<T_TOKENS / 256, 256, 0, stream>>>(topidx, topg, offs, fill, tok, gate);

    dim3 blk(512);
    if (cvt_ew) {
        // L1 merged: shared (16 m-tiles) + experts (<=40 padded m-tiles), N=HID
        gemm_moe256<1><<<dim3((MT_SH2 + MT_EX2) * (HID / 256)), blk, 0, stream>>>(
            xb, xb, sw1b, ew1b, offs, tok, gate, hidS, hidE, nullptr);
        // L2 merged: N=DM, all-atomicAdd into pre-zeroed out
        gemm_moe256<2><<<dim3((MT_SH2 + MT_EX2) * (DM / 256)), blk, 0, stream>>>(
            hidS, hidE, sw2b, ew2b, offs, tok, gate, nullptr, nullptr, out);
    } else {
        // shared-only via gemm_moe256 (grid limited to shared section),
        // experts via in-flight-convert fallback (real slot counts only).
        gemm_moe256<1><<<dim3(MT_SH2 * (HID / 256)), blk, 0, stream>>>(
            xb, xb, sw1b, nullptr, offs, tok, gate, hidS, nullptr, nullptr);
        gemm_bt<float, 2><<<dim3(HID / 128, T_TOKENS / 128, NE), dim3(256), 0, stream>>>(
            xb, DM, ew1, DM, (long)HID * DM, DM, 0,
            cnt, offs, tok, gate, hidE, HID, nullptr, 0);
        gemm_moe256<2><<<dim3(MT_SH2 * (DM / 256)), blk, 0, stream>>>(
            hidS, hidE, sw2b, nullptr, offs, tok, gate, nullptr, nullptr, out);
        gemm_bt<float, 3><<<dim3(DM / 128, T_TOKENS / 128, NE), dim3(256), 0, stream>>>(
            hidE, HID, ew2, HID, (long)DM * HID, HID, 0,
            cnt, offs, tok, gate, nullptr, 0, out, DM);
    }
}

// Round 9
// 916.814 us; speedup vs baseline: 1.0768x; 1.0264x over previous
//
#include <hip/hip_runtime.h>

// MoE FFN: D=1024, H=4096, E=8, top-2, T=4096 tokens, fp32 in/out, bf16 MFMA compute.
// R11: XCD co-residency round. Nine rounds of schedule work were all neutral at
// 340-420 TF; R10's counters show P2 FETCH = 490 MB vs 173 ideal = A-panels
// fetched ~4x (their 4 n-blocks land on 4 XCDs under round-robin). Fix: each
// XCD gets a CONTIGUOUS slab of m-tiles, n-fastest inside, so A-panel sharers
// are co-resident IN SPACE on one XCD's L2 (R6 failed because it serialized
// sharers in time). Slab partition is active-count-aware (reads offs[NE]) so
// the padded tail doesn't idle a whole XCD. Only the block->(mt,nx) mapping
// changed vs R10; the 8-phase loop, layouts, epilogues are untouched.

#define T_TOKENS 4096
#define DM 1024
#define HID 4096
#define NE 8
#define MT_SH2 (T_TOKENS / 256)                  // 16 shared m-tiles (256-rows)
#define SLOTS_MAX (2 * T_TOKENS + 256 * NE)      // 10240 padded expert slots max
#define MT_EX2 (SLOTS_MAX / 256)                 // 40 expert m-tiles max

typedef __attribute__((ext_vector_type(8))) short short8;
typedef __attribute__((ext_vector_type(4))) float f32x4;
typedef unsigned short u16;

__device__ __forceinline__ u16 f2b(float f) {
    unsigned u = __builtin_bit_cast(unsigned, f);
    u += 0x7FFFu + ((u >> 16) & 1u);   // round-to-nearest-even
    return (u16)(u >> 16);
}

__device__ __forceinline__ uint4 load8(const u16* p) {
    return *(const uint4*)p;           // 8 bf16 = 16 B
}
__device__ __forceinline__ uint4 load8(const float* p) {
    const float4* q = (const float4*)p;
    float4 a = q[0], b = q[1];
    uint4 r;
    r.x = (unsigned)f2b(a.x) | ((unsigned)f2b(a.y) << 16);
    r.y = (unsigned)f2b(a.z) | ((unsigned)f2b(a.w) << 16);
    r.z = (unsigned)f2b(b.x) | ((unsigned)f2b(b.y) << 16);
    r.w = (unsigned)f2b(b.z) | ((unsigned)f2b(b.w) << 16);
    return r;
}

// async 16B global -> LDS (wave-uniform lds base + lane*16)
__device__ __forceinline__ void gld16(const u16* g, u16* lds) {
    __builtin_amdgcn_global_load_lds(
        (const __attribute__((address_space(1))) void*)g,
        (__attribute__((address_space(3))) void*)lds, 16, 0, 0);
}

#define BARRIER() do { __builtin_amdgcn_s_barrier(); asm volatile("" ::: "memory"); } while (0)

// ---- fused fp32 -> bf16 conversion of all tensors --------------------------
constexpr long CN0 = (long)T_TOKENS * DM;        // x
constexpr long CN1 = CN0 + (long)HID * DM;       // sw1
constexpr long CN2 = CN1 + (long)DM * HID;       // sw2
constexpr long CN3 = CN2 + (long)NE * HID * DM;  // ew1
constexpr long CN4 = CN3 + (long)NE * DM * HID;  // ew2

template<bool FULL>
__global__ __launch_bounds__(256) void cvt_all_kernel(
    const float* __restrict__ x,  const float* __restrict__ sw1,
    const float* __restrict__ sw2, const float* __restrict__ ew1,
    const float* __restrict__ ew2,
    u16* __restrict__ xb, u16* __restrict__ sw1b, u16* __restrict__ sw2b,
    u16* __restrict__ ew1b, u16* __restrict__ ew2b) {
    long i = ((long)blockIdx.x * 256 + threadIdx.x) * 8;
    const float* s; u16* d; long base;
    if (i < CN0)      { s = x;   d = xb;   base = 0;   }
    else if (i < CN1) { s = sw1; d = sw1b; base = CN0; }
    else if (i < CN2) { s = sw2; d = sw2b; base = CN1; }
    else if (FULL && i < CN3) { s = ew1; d = ew1b; base = CN2; }
    else if (FULL && i < CN4) { s = ew2; d = ew2b; base = CN3; }
    else return;
    long j = i - base;
    *(uint4*)(d + j) = load8(s + j);
}

// ---- gating (fp32: bf16 logits would flip near-tie expert picks) -----------
__global__ __launch_bounds__(256) void gate_kernel(const float* __restrict__ x,
                                                   const float* __restrict__ gw,
                                                   int* __restrict__ cnt,
                                                   int2* __restrict__ topidx,
                                                   float2* __restrict__ topg) {
    int t = blockIdx.x * 4 + (threadIdx.x >> 6);
    int lane = threadIdx.x & 63;
    const float* xr = x + (long)t * DM;
    float s[NE];
#pragma unroll
    for (int e = 0; e < NE; e++) s[e] = 0.f;
    for (int i = lane; i < DM; i += 64) {
        float xv = xr[i];
#pragma unroll
        for (int e = 0; e < NE; e++) s[e] += xv * gw[e * DM + i];
    }
#pragma unroll
    for (int e = 0; e < NE; e++)
        for (int o = 32; o > 0; o >>= 1) s[e] += __shfl_down(s[e], o);
    if (lane == 0) {
        int i0 = 0; float l0 = s[0];
#pragma unroll
        for (int e = 1; e < NE; e++) if (s[e] > l0) { l0 = s[e]; i0 = e; }
        int i1 = -1; float l1 = -1e30f;
#pragma unroll
        for (int e = 0; e < NE; e++) if (e != i0 && s[e] > l1) { l1 = s[e]; i1 = e; }
        float e1 = __expf(l1 - l0);
        float inv = 1.f / (1.f + e1);
        topidx[t] = make_int2(i0, i1);
        topg[t]   = make_float2(inv, e1 * inv);
        atomicAdd(&cnt[i0], 1);
        atomicAdd(&cnt[i1], 1);
    }
}

// offs padded to 256-aligned ranges: every expert m-tile is FULL (padding
// slots have tok=0/gate=0 from the memset -> contribute exactly 0 in L2).
__global__ void prefix_kernel(const int* __restrict__ cnt, int* __restrict__ offs) {
    if (threadIdx.x == 0) {
        int a = 0;
        for (int e = 0; e < NE; e++) {
            offs[e] = a;
            a += cnt[e];
            a = (a + 255) & ~255;
        }
        offs[NE] = a;   // total padded slots
    }
}

__global__ __launch_bounds__(256) void scatter_kernel(const int2* __restrict__ topidx,
                                                      const float2* __restrict__ topg,
                                                      const int* __restrict__ offs,
                                                      int* __restrict__ fill,
                                                      int* __restrict__ tok,
                                                      float* __restrict__ gate) {
    int t = blockIdx.x * 256 + threadIdx.x;
    if (t >= T_TOKENS) return;
    int2 ix = topidx[t]; float2 g = topg[t];
    int p = atomicAdd(&fill[ix.x], 1);
    int sl = offs[ix.x] + p;
    tok[sl] = t; gate[sl] = g.x;
    p = atomicAdd(&fill[ix.y], 1);
    sl = offs[ix.y] + p;
    tok[sl] = t; gate[sl] = g.y;
}

// ---- merged grouped GEMM, 256x256, BK=64, 8 waves, m201 8-phase schedule ---
// C[M,N] = A[M,K] * B[N,K]^T, bf16.
// XCD-slab mapping (assumes XCD = bid % 8, the validated T1 model): XCD x owns
// a contiguous slab of ACTIVE m-tiles [x*per, (x+1)*per), n-fastest inside.
// -> one m-tile's NX n-blocks are CO-RESIDENT on one XCD (A-panel fetched into
// that L2 once); slab m-tiles belong to 1-2 experts marching K in lockstep
// (B panels shared). per = ceil(NMa/8) from offs[NE] read in-kernel, so the
// padded tail doesn't idle an entire XCD.
// LDS: As/Bs[2 dbuf][2 ks][256 rows x 32 K]; chunk swizzle (verified
// 0-conflict): chunk p = row*4 + (kg^((row>>1)&3)); gld16 dest linear, swizzle
// on the per-lane GLOBAL source address.
// Phase plan per K-tile j: 4 phases of {issue 1 unit -> (ks-start: counted
// vmcnt + barrier) -> ds_read frags -> setprio(1) 16 MFMA setprio(0) ->
// barrier}. Steady state 5 units / 10 loads in flight (vmcnt(10)); tail 8/4/0.
// PHASE 1: K=DM,  N=HID; silu -> bf16 into hS (shared) / hE (slots)
// PHASE 2: K=HID, N=DM;  atomicAdd f32 into pre-zeroed out
template<int PHASE>
__global__ __launch_bounds__(512, 2)
void gemm_moe256(const u16* __restrict__ Ash, const u16* __restrict__ Aex,
                 const u16* __restrict__ Bsh, const u16* __restrict__ Bex,
                 const int* __restrict__ offs,
                 const int* __restrict__ tok, const float* __restrict__ gate,
                 u16* __restrict__ hS, u16* __restrict__ hE,
                 float* __restrict__ out) {
    constexpr int KK = (PHASE == 1) ? DM : HID;
    constexpr int NX = (PHASE == 1) ? HID / 256 : DM / 256;
    constexpr long strideB = (long)HID * DM;

    // ---- XCD-slab block mapping (replaces natural n-fastest order) ----
    const int NM_phys = gridDim.x / NX;                 // 56 (merged) or 16
    int NMa = MT_SH2 + (offs[NE] >> 8);                 // active m-tiles
    if (NMa > NM_phys) NMa = NM_phys;                   // shared-only launch
    const int per = (NMa + 7) >> 3;                     // slab size per XCD
    const int x   = blockIdx.x & 7;                     // XCD under round-robin
    const int i   = blockIdx.x >> 3;                    // index within XCD
    if (i >= per * NX) return;                          // beyond slab capacity
    const int mt  = x * per + i / NX;
    const int nx  = i % NX;
    if (mt >= NMa) return;                              // tail slab underfull
    const int n0 = nx * 256;

    const bool sh = (mt < MT_SH2);
    int m0;
    const u16* Ab;
    const u16* B;
    if (sh) {
        m0 = mt * 256;
        Ab = Ash; B = Bsh;
    } else {
        m0 = (mt - MT_SH2) * 256;                       // < offs[NE] by mt<NMa
        int e = 0;
#pragma unroll
        for (int k = 1; k < NE; k++) e += (m0 >= offs[k]);
        Ab = Aex;
        B = Bex + (long)e * strideB;
    }

    __shared__ u16 As[2][2][256 * 32];   // [dbuf][ks][row*32 + swz chunk] 16KB/unit
    __shared__ u16 Bs[2][2][256 * 32];

    const int tid  = threadIdx.x;
    const int lane = tid & 63;
    const int wid  = tid >> 6;           // 0..7
    const int wm   = (wid >> 2) * 128;   // wave M offset: 0 / 128
    const int wn   = (wid & 3) * 64;     // wave N offset: 0/64/128/192
    const int lr   = lane & 15;

    // Staging: one unit = 1024 chunks of 16B; thread covers p = i*512+tid.
    const u16* aP[2]; const u16* bP[2]; int ldso[2];
#pragma unroll
    for (int q = 0; q < 2; q++) {
        int p = q * 512 + tid;
        int r = p >> 2;                                // 0..255
        int kg = (p & 3) ^ ((r >> 1) & 3);
        long arow;
        if (sh)                        arow = m0 + r;
        else if constexpr (PHASE == 1) arow = tok[m0 + r];
        else                           arow = m0 + r;
        aP[q] = Ab + arow * (long)KK + kg * 8;
        bP[q] = B + (long)(n0 + r) * KK + kg * 8;
        ldso[q] = (q * 512 + wid * 64) * 8;            // wave-uniform base
    }

    // Fragment read offsets within a unit (verified conflict-free pattern).
    const int key = (lr >> 1) & 3;
    const int kgx = (lane >> 4) ^ key;
    const int aoe = (wm + lr) * 32 + kgx * 8;
    const int boe = (wn + lr) * 32 + kgx * 8;

    f32x4 acc[8][4];
#pragma unroll
    for (int mi = 0; mi < 8; mi++)
#pragma unroll
        for (int ni = 0; ni < 4; ni++)
            acc[mi][ni] = (f32x4){0.f, 0.f, 0.f, 0.f};

    auto stage_unit = [&](int u) {       // 2 gld16/thread (16KB block-wide)
        const int jj = u >> 2, ks = (u >> 1) & 1, isB = u & 1;
        const long kb = (long)jj * 64 + ks * 32;
        u16* dst = isB ? &Bs[jj & 1][ks][0] : &As[jj & 1][ks][0];
        const u16* const* gp = isB ? bP : aP;
#pragma unroll
        for (int q = 0; q < 2; q++) gld16(gp[q] + kb, dst + ldso[q]);
    };

    const int nt  = KK >> 6;             // 64-K tiles: 16 (P1) / 64 (P2)
    const int NTU = nt * 4;              // total stage units
    int isd = 0;
    for (; isd < 6; ++isd) stage_unit(isd);   // prologue: 6 units / 12 loads

#define ISSUE() do { if (isd < NTU) { stage_unit(isd); ++isd; } } while (0)
#define MFMA16(A_, B_, MH_) do {                                              \
    __builtin_amdgcn_s_setprio(1);                                            \
    _Pragma("unroll")                                                         \
    for (int m_ = 0; m_ < 4; m_++)                                            \
        _Pragma("unroll")                                                     \
        for (int n_ = 0; n_ < 4; n_++)                                        \
            acc[(MH_) * 4 + m_][n_] = __builtin_amdgcn_mfma_f32_16x16x32_bf16(\
                (A_)[m_], (B_)[n_], acc[(MH_) * 4 + m_][n_], 0, 0, 0);        \
    __builtin_amdgcn_s_setprio(0);                                            \
} while (0)

    for (int j = 0; j < nt; ++j) {
        const int cb  = j & 1;
        const int rem = nt - 1 - j;
        // ---- phase 0 (ks=0, mh=0) ----
        ISSUE();
        if (rem >= 1) asm volatile("s_waitcnt vmcnt(10)" ::: "memory");
        else          asm volatile("s_waitcnt vmcnt(4)"  ::: "memory");
        BARRIER();                       // units (j,Ak0),(j,Bk0) landed, all waves
        short8 b0[4], a0[4];
#pragma unroll
        for (int n_ = 0; n_ < 4; n_++) b0[n_] = *(const short8*)&Bs[cb][0][boe + n_ * 512];
#pragma unroll
        for (int m_ = 0; m_ < 4; m_++) a0[m_] = *(const short8*)&As[cb][0][aoe + m_ * 512];
        MFMA16(a0, b0, 0);
        BARRIER();
        // ---- phase 1 (ks=0, mh=1) ----
        ISSUE();
        short8 a1[4];
#pragma unroll
        for (int m_ = 0; m_ < 4; m_++) a1[m_] = *(const short8*)&As[cb][0][aoe + (4 + m_) * 512];
        BARRIER();
        MFMA16(a1, b0, 1);
        BARRIER();
        // ---- phase 2 (ks=1, mh=0) ----
        ISSUE();
        if (rem >= 2)      asm volatile("s_waitcnt vmcnt(10)" ::: "memory");
        else if (rem == 1) asm volatile("s_waitcnt vmcnt(8)"  ::: "memory");
        else               asm volatile("s_waitcnt vmcnt(0)"  ::: "memory");
        BARRIER();                       // units (j,Ak1),(j,Bk1) landed
        short8 b1[4], a2[4];
#pragma unroll
        for (int n_ = 0; n_ < 4; n_++) b1[n_] = *(const short8*)&Bs[cb][1][boe + n_ * 512];
#pragma unroll
        for (int m_ = 0; m_ < 4; m_++) a2[m_] = *(const short8*)&As[cb][1][aoe + m_ * 512];
        MFMA16(a2, b1, 0);
        BARRIER();
        // ---- phase 3 (ks=1, mh=1) ----
        ISSUE();
        short8 a3[4];
#pragma unroll
        for (int m_ = 0; m_ < 4; m_++) a3[m_] = *(const short8*)&As[cb][1][aoe + (4 + m_) * 512];
        BARRIER();
        MFMA16(a3, b1, 1);
        BARRIER();
    }
#undef ISSUE
#undef MFMA16

    // Epilogue. C/D layout: col = lane&15, row = (lane>>4)*4 + reg  [m89-verified]
    const int r4 = (lane >> 4) * 4;
    const int cl = lane & 15;
#pragma unroll
    for (int mi = 0; mi < 8; mi++) {
#pragma unroll
        for (int rr = 0; rr < 4; rr++) {
            int row = m0 + wm + mi * 16 + r4 + rr;
            int tt = 0; float g = 0.f;
            if constexpr (PHASE == 2) {
                if (!sh) { tt = tok[row]; g = gate[row]; }
            }
#pragma unroll
            for (int ni = 0; ni < 4; ni++) {
                int col = n0 + wn + ni * 16 + cl;
                float v = acc[mi][ni][rr];
                if constexpr (PHASE == 1) {
                    float s2 = v / (1.f + __expf(-v));
                    if (sh) hS[(long)row * HID + col] = f2b(s2);
                    else    hE[(long)row * HID + col] = f2b(s2);
                } else {
                    if (sh) atomicAdd(&out[(long)row * DM + col], v);
                    else    atomicAdd(&out[(long)tt * DM + col], g * v);
                }
            }
        }
    }
}

// ---- fallback sync GEMM (fp32 B in-flight convert) for small-ws case -------
template<typename TB, int MODE>
__global__ __launch_bounds__(256)
void gemm_bt(const u16* __restrict__ A, int lda,
             const TB* __restrict__ Bbase, int ldb, long strideB, int K,
             int Mstatic,
             const int* __restrict__ cnt, const int* __restrict__ offs,
             const int* __restrict__ tok_of_slot, const float* __restrict__ gate_of_slot,
             u16* __restrict__ Cb, int ldcb,
             float* __restrict__ Cf, int ldcf) {
    int M = Mstatic, base = 0;
    const TB* B = Bbase;
    if constexpr (MODE >= 2) {
        int e = blockIdx.z;
        base = offs[e];
        M = cnt[e];
        B = Bbase + (long)e * strideB;
    }
    const int m0 = blockIdx.y * 128;
    if (m0 >= M) return;
    const int n0 = blockIdx.x * 128;

    __shared__ u16 As[128][40];
    __shared__ u16 Bs[128][40];

    const int tid  = threadIdx.x;
    const int lane = tid & 63;
    const int wid  = tid >> 6;
    const int wm   = (wid >> 1) * 64;
    const int wn   = (wid & 1) * 64;
    const int lr   = lane & 15;
    const int lk   = (lane >> 4) * 8;

    int arow_r[2], akc[2];
    long aoff[2], boff[2];
#pragma unroll
    for (int i = 0; i < 2; i++) {
        int c = tid + i * 256;
        int r = c >> 2, kc = (c & 3) * 8;
        arow_r[i] = r; akc[i] = kc;
        int rr = m0 + r;
        if (rr >= M) rr = M - 1;
        long grow;
        if constexpr (MODE == 2)      grow = tok_of_slot[base + rr];
        else if constexpr (MODE == 3) grow = (long)(base + rr);
        else                          grow = rr;
        aoff[i] = grow * (long)lda + kc;
        boff[i] = (long)(n0 + r) * ldb + kc;
    }

    f32x4 acc[4][4];
#pragma unroll
    for (int mi = 0; mi < 4; mi++)
#pragma unroll
        for (int ni = 0; ni < 4; ni++)
            acc[mi][ni] = (f32x4){0.f, 0.f, 0.f, 0.f};

    for (int k0 = 0; k0 < K; k0 += 32) {
#pragma unroll
        for (int i = 0; i < 2; i++) {
            *(uint4*)&As[arow_r[i]][akc[i]] = load8(A + aoff[i] + k0);
            *(uint4*)&Bs[arow_r[i]][akc[i]] = load8(B + boff[i] + k0);
        }
        __syncthreads();
        short8 af[4], bfr[4];
#pragma unroll
        for (int mi = 0; mi < 4; mi++) af[mi]  = *(const short8*)&As[wm + mi * 16 + lr][lk];
#pragma unroll
        for (int ni = 0; ni < 4; ni++) bfr[ni] = *(const short8*)&Bs[wn + ni * 16 + lr][lk];
#pragma unroll
        for (int mi = 0; mi < 4; mi++)
#pragma unroll
            for (int ni = 0; ni < 4; ni++)
                acc[mi][ni] = __builtin_amdgcn_mfma_f32_16x16x32_bf16(af[mi], bfr[ni],
                                                                      acc[mi][ni], 0, 0, 0);
        __syncthreads();
    }

    const int r4 = (lane >> 4) * 4;
    const int cl = lane & 15;
#pragma unroll
    for (int mi = 0; mi < 4; mi++) {
#pragma unroll
        for (int rr = 0; rr < 4; rr++) {
            int row = m0 + wm + mi * 16 + r4 + rr;
            if constexpr (MODE >= 2) { if (row >= M) continue; }
            int t = 0; float g = 0.f;
            if constexpr (MODE == 3) {
                t = tok_of_slot[base + row];
                g = gate_of_slot[base + row];
            }
#pragma unroll
            for (int ni = 0; ni < 4; ni++) {
                int col = n0 + wn + ni * 16 + cl;
                float v = acc[mi][ni][rr];
                if constexpr (MODE == 2) {
                    float s = v / (1.f + __expf(-v));
                    Cb[(long)(base + row) * ldcb + col] = f2b(s);
                } else if constexpr (MODE == 3) {
                    atomicAdd(&Cf[(long)t * ldcf + col], g * v);
                }
            }
        }
    }
}

extern "C" void kernel_launch(void* const* d_in, const int* in_sizes, int n_in,
                              void* d_out, int out_size, void* d_ws, size_t ws_size,
                              hipStream_t stream) {
    const float* x   = (const float*)d_in[0];
    const float* sw1 = (const float*)d_in[1];
    const float* sw2 = (const float*)d_in[2];
    const float* ew1 = (const float*)d_in[3];
    const float* ew2 = (const float*)d_in[4];
    const float* gw  = (const float*)d_in[5];
    float* out = (float*)d_out;

    char* ws = (char*)d_ws;
    size_t off = 0;
    auto alloc = [&](size_t bytes) -> char* {
        off = (off + 255) & ~(size_t)255;
        char* p = ws + off;
        off += bytes;
        return p;
    };

    int*    meta   = (int*)alloc(256);          // cnt[8] | fill[8] | offs[9]
    int*    cnt    = meta;
    int*    fill   = meta + 8;
    int*    offs   = meta + 16;
    int2*   topidx = (int2*)alloc((size_t)T_TOKENS * 8);
    float2* topg   = (float2*)alloc((size_t)T_TOKENS * 8);
    int*    tok    = (int*)alloc((size_t)SLOTS_MAX * 4);
    float*  gate   = (float*)alloc((size_t)SLOTS_MAX * 4);
    u16* xb   = (u16*)alloc((size_t)T_TOKENS * DM * 2);
    u16* sw1b = (u16*)alloc((size_t)HID * DM * 2);
    u16* sw2b = (u16*)alloc((size_t)DM * HID * 2);
    u16* hidS = (u16*)alloc((size_t)T_TOKENS * HID * 2);
    u16* hidE = (u16*)alloc((size_t)SLOTS_MAX * HID * 2);

    const size_t ew_bytes = (size_t)NE * HID * DM * 2;   // 64 MB each
    bool cvt_ew = (ws_size >= off + 2 * ew_bytes + 1024);
    u16 *ew1b = nullptr, *ew2b = nullptr;
    if (cvt_ew) {
        ew1b = (u16*)alloc(ew_bytes);
        ew2b = (u16*)alloc(ew_bytes);
    }

    hipMemsetAsync(meta, 0, 64, stream);                         // cnt+fill
    hipMemsetAsync(tok, 0, (size_t)SLOTS_MAX * 4, stream);       // padding -> token 0
    hipMemsetAsync(gate, 0, (size_t)SLOTS_MAX * 4, stream);      // padding -> gate 0
    hipMemsetAsync(out, 0, (size_t)T_TOKENS * DM * 4, stream);   // L2 is all-atomicAdd

    if (cvt_ew)
        cvt_all_kernel<true><<<(int)(CN4 / 2048), 256, 0, stream>>>(
            x, sw1, sw2, ew1, ew2, xb, sw1b, sw2b, ew1b, ew2b);
    else
        cvt_all_kernel<false><<<(int)(CN2 / 2048), 256, 0, stream>>>(
            x, sw1, sw2, nullptr, nullptr, xb, sw1b, sw2b, nullptr, nullptr);

    gate_kernel<<<T_TOKENS / 4, 256, 0, stream>>>(x, gw, cnt, topidx, topg);
    prefix_kernel<<<1, 64, 0, stream>>>(cnt, offs);
    scatter_kernel<<<T_TOKENS / 256, 256, 0, stream>>>(topidx, topg, offs, fill, tok, gate);

    dim3 blk(512);
    if (cvt_ew) {
        // L1 merged: shared (16 m-tiles) + experts (<=40 padded m-tiles), N=HID
        gemm_moe256<1><<<dim3((MT_SH2 + MT_EX2) * (HID / 256)), blk, 0, stream>>>(
            xb, xb, sw1b, ew1b, offs, tok, gate, hidS, hidE, nullptr);
        // L2 merged: N=DM, all-atomicAdd into pre-zeroed out
        gemm_moe256<2><<<dim3((MT_SH2 + MT_EX2) * (DM / 256)), blk, 0, stream>>>(
            hidS, hidE, sw2b, ew2b, offs, tok, gate, nullptr, nullptr, out);
    } else {
        // shared-only via gemm_moe256 (grid limited to shared section),
        // experts via in-flight-convert fallback (real slot counts only).
        gemm_moe256<1><<<dim3(MT_SH2 * (HID / 256)), blk, 0, stream>>>(
            xb, xb, sw1b, nullptr, offs, tok, gate, hidS, nullptr, nullptr);
        gemm_bt<float, 2><<<dim3(HID / 128, T_TOKENS / 128, NE), dim3(256), 0, stream>>>(
            xb, DM, ew1, DM, (long)HID * DM, DM, 0,
            cnt, offs, tok, gate, hidE, HID, nullptr, 0);
        gemm_moe256<2><<<dim3(MT_SH2 * (DM / 256)), blk, 0, stream>>>(
            hidS, hidE, sw2b, nullptr, offs, tok, gate, nullptr, nullptr, out);
        gemm_bt<float, 3><<<dim3(DM / 128, T_TOKENS / 128, NE), dim3(256), 0, stream>>>(
            hidE, HID, ew2, HID, (long)DM * HID, HID, 0,
            cnt, offs, tok, gate, nullptr, 0, out, DM);
    }
}